// Round 10
// baseline (492.972 us; speedup 1.0000x reference)
//
#include <hip/hip_runtime.h>
#include <cstdint>
#include <cstddef>

// ---- problem constants ----
#define BB    2048
#define LL    200
#define GR    8      // batch rows per scan block
#define MR    8      // batch rows per block in MLP

typedef __attribute__((ext_vector_type(4))) float f32x4;
typedef __attribute__((ext_vector_type(8))) short s16x8;

__device__ __forceinline__ float fastrcp(float x) { return __builtin_amdgcn_rcpf(x); }
__device__ __forceinline__ float sigmf(float x) { return fastrcp(1.f + __expf(-x)); }
__device__ __forceinline__ float tanh2(float x) {
    return __builtin_fmaf(2.f, fastrcp(1.f + __expf(-2.f * x)), -1.f);
}
__device__ __forceinline__ float dot4(float4 a, float4 b) {
    return a.x * b.x + a.y * b.y + a.z * b.z + a.w * b.w;
}
__device__ __forceinline__ float4 ld4(const float* p) { return *(const float4*)p; }

__device__ __forceinline__ unsigned short f2bf(float f) {  // RNE
    union { float f; unsigned u; } v; v.f = f;
    unsigned r = (v.u + 0x7FFFu + ((v.u >> 16) & 1u)) >> 16;
    return (unsigned short)r;
}
__device__ __forceinline__ float bf2f(unsigned short b) {
    unsigned u = ((unsigned)b) << 16;
    union { unsigned u; float f; } v; v.u = u;
    return v.f;
}
__device__ __forceinline__ s16x8 pack8g(const float* p) {
    float4 a = ld4(p), b = ld4(p + 4);
    s16x8 o;
    o[0] = (short)f2bf(a.x); o[1] = (short)f2bf(a.y);
    o[2] = (short)f2bf(a.z); o[3] = (short)f2bf(a.w);
    o[4] = (short)f2bf(b.x); o[5] = (short)f2bf(b.y);
    o[6] = (short)f2bf(b.z); o[7] = (short)f2bf(b.w);
    return o;
}
#define MFMA(a, b, c) __builtin_amdgcn_mfma_f32_16x16x32_bf16((a), (b), (c), 0, 0, 0)

// Raw barrier: LDS-drain only; global prefetch loads stay in flight.
#define BAR() do { \
    asm volatile("s_waitcnt lgkmcnt(0)" ::: "memory"); \
    __builtin_amdgcn_sched_barrier(0); \
    __builtin_amdgcn_s_barrier(); \
    __builtin_amdgcn_sched_barrier(0); \
} while (0)

// redistribute f32x4 acc (8 rows spread as lanes0-31:q0..3) -> every lane 2 rows
#define RED2(A, O0, O1) { \
    float s2_ = __shfl(A[2], srcl), s3_ = __shfl(A[3], srcl); \
    O0 = hi ? s2_ : A[0]; O1 = hi ? s3_ : A[1]; \
}

// ---- K-1: convert hist_table fp32 -> bf16 once ----
__global__ __launch_bounds__(256) void cvt_hist(const float* __restrict__ src,
                                                unsigned short* __restrict__ dst, int n8) {
    int i = blockIdx.x * 256 + threadIdx.x;
    if (i < n8) *(s16x8*)(dst + (size_t)i * 8) = pack8g(src + (size_t)i * 8);
}

// ---- K0: transpose small weight matrices ----
__global__ void transpose_kernel(const float* __restrict__ src, float* __restrict__ dst,
                                 int rows, int cols) {
    int k = blockIdx.x;
    for (int j = threadIdx.x; j < rows; j += blockDim.x)
        dst[(size_t)k * rows + j] = src[(size_t)j * cols + k];
}

// ---- K1: target = item_table[item_id] @ proj_W^T ----
__global__ __launch_bounds__(128) void target_kernel(
    const int* __restrict__ item_id, const float* __restrict__ item_table,
    const float* __restrict__ projW, float* __restrict__ target) {
    __shared__ float ie[64];
    int b = blockIdx.x, d = threadIdx.x;
    if (d < 64) ie[d] = item_table[(size_t)item_id[b] * 64 + d];
    __syncthreads();
    float acc = 0.f;
    const float* w = projW + (size_t)d * 64;
#pragma unroll
    for (int k = 0; k < 64; k += 4) acc += dot4(ld4(&ie[k]), ld4(w + k));
    target[(size_t)b * 128 + d] = acc;
}

// ---- K2: GRU scan v10 — inline score, register h-store (natural layout) ----
// h2 record (per block, t): 1024 shorts, natural [row][dim] bf16.
__global__ __launch_bounds__(512, 2) void gru_v10(
    const int* __restrict__ hseq, const unsigned short* __restrict__ hist_bf,
    const float* __restrict__ Wi, const float* __restrict__ Wh,
    const float* __restrict__ bi, const float* __restrict__ bh,
    const float* __restrict__ target,
    unsigned short* __restrict__ h2, float* __restrict__ scores) {
    __shared__ alignas(16) unsigned short hf[2][2048];
    __shared__ float scoreb[2][64];   // [parity][row*8 + wave]
    __shared__ int sq[GR * LL];
    const int tid = threadIdx.x;
    const int w = tid >> 6, lane = tid & 63;
    const int b0 = blockIdx.x * GR;
    const int cb = (w << 4) | (lane & 15);
    const int kc_ = cb >> 5, kq_ = (cb >> 3) & 3, jj = cb & 7;
    const int srcl = lane & 31;
    const bool hi = lane >= 32;
    const int rowb = ((lane & 31) >> 4) * 4 + (hi ? 2 : 0);
    const int xrow = lane & 7;
    const int xko = (lane >> 4) * 8;
    unsigned short* const h2p = h2 + (size_t)blockIdx.x * (LL * 1024);
    s16x8 wir[4], wiz[4], win[4], whr[4], whz[4], whn[4];
    {
        int c = lane & 15, kg = (lane >> 4) * 8;
#pragma unroll
        for (int kc = 0; kc < 4; ++kc) {
            int ko = kc * 32 + kg;
            wir[kc] = pack8g(Wi + (size_t)(w * 16 + c) * 128 + ko);
            wiz[kc] = pack8g(Wi + (size_t)(128 + w * 16 + c) * 128 + ko);
            win[kc] = pack8g(Wi + (size_t)(256 + w * 16 + c) * 128 + ko);
            whr[kc] = pack8g(Wh + (size_t)(w * 16 + c) * 128 + ko);
            whz[kc] = pack8g(Wh + (size_t)(128 + w * 16 + c) * 128 + ko);
            whn[kc] = pack8g(Wh + (size_t)(256 + w * 16 + c) * 128 + ko);
        }
    }
    const float b_r = bi[cb] + bh[cb];
    const float b_z = bi[128 + cb] + bh[128 + cb];
    const float bi_n = bi[256 + cb], bh_n = bh[256 + cb];
    const float tg0 = target[(size_t)(b0 + rowb) * 128 + cb];
    const float tg1 = target[(size_t)(b0 + rowb + 1) * 128 + cb];
    float hold0 = 0.f, hold1 = 0.f;
    for (int i = tid; i < 2048; i += 512) { hf[0][i] = 0; hf[1][i] = 0; }
    for (int i = tid; i < GR * LL; i += 512)
        sq[i] = hseq[(size_t)(b0 + i / LL) * LL + i % LL];
    __syncthreads();

    s16x8 xA0, xA1, xA2, xA3, xB0, xB1, xB2, xB3;
    f32x4 xr, xz, xn;   // x-side partials for the NEXT step
#define XLOAD(TT, X0, X1, X2, X3) { \
    int idx_ = sq[xrow * LL + (TT)]; \
    const unsigned short* xp_ = hist_bf + ((size_t)idx_ << 7) + xko; \
    X0 = *(const s16x8*)(xp_);      X1 = *(const s16x8*)(xp_ + 32); \
    X2 = *(const s16x8*)(xp_ + 64); X3 = *(const s16x8*)(xp_ + 96); \
}
    XLOAD(0, xA0, xA1, xA2, xA3);
    xr = (f32x4){0, 0, 0, 0}; xz = xr; xn = xr;
    xr = MFMA(xA0, wir[0], xr); xz = MFMA(xA0, wiz[0], xz); xn = MFMA(xA0, win[0], xn);
    xr = MFMA(xA1, wir[1], xr); xz = MFMA(xA1, wiz[1], xz); xn = MFMA(xA1, win[1], xn);
    xr = MFMA(xA2, wir[2], xr); xz = MFMA(xA2, wiz[2], xz); xn = MFMA(xA2, win[2], xn);
    xr = MFMA(xA3, wir[3], xr); xz = MFMA(xA3, wiz[3], xz); xn = MFMA(xA3, win[3], xn);
    XLOAD(1, xB0, xB1, xB2, xB3);

#define GSTEP(TT, RD, XU0, XU1, XU2, XU3, XL0, XL1, XL2, XL3) { \
    const int tt = (TT); \
    if (tt > 0 && lane == 16) {  /* finalize score tt-1 */ \
        float s = 0.f; \
        _Pragma("unroll") for (int wv = 0; wv < 8; ++wv) s += scoreb[RD ^ 1][w * 8 + wv]; \
        scores[(size_t)(b0 + w) * LL + tt - 1] = s * 0.08838834764831845f; \
    } \
    f32x4 ar = xr, az = xz, ain = xn; \
    f32x4 ahn = {0, 0, 0, 0}; \
    _Pragma("unroll") for (int kc = 0; kc < 4; ++kc) { \
        s16x8 ha = *(const s16x8*)&hf[RD][(kc * 64 + lane) * 8]; \
        ar = MFMA(ha, whr[kc], ar); az = MFMA(ha, whz[kc], az); ahn = MFMA(ha, whn[kc], ahn); \
    } \
    xr = (f32x4){0, 0, 0, 0}; xz = xr; xn = xr; \
    xr = MFMA(XU0, wir[0], xr); xz = MFMA(XU0, wiz[0], xz); xn = MFMA(XU0, win[0], xn); \
    xr = MFMA(XU1, wir[1], xr); xz = MFMA(XU1, wiz[1], xz); xn = MFMA(XU1, win[1], xn); \
    xr = MFMA(XU2, wir[2], xr); xz = MFMA(XU2, wiz[2], xz); xn = MFMA(XU2, win[2], xn); \
    xr = MFMA(XU3, wir[3], xr); xz = MFMA(XU3, wiz[3], xz); xn = MFMA(XU3, win[3], xn); \
    XLOAD(tt + 2 < LL ? tt + 2 : LL - 1, XL0, XL1, XL2, XL3); \
    { \
        float r0x, r1x, z0x, z1x, ni0, ni1, nh0, nh1; \
        RED2(ar, r0x, r1x); RED2(az, z0x, z1x); \
        RED2(ain, ni0, ni1); RED2(ahn, nh0, nh1); \
        float r0 = sigmf(r0x + b_r), z0 = sigmf(z0x + b_z); \
        float n0 = tanh2(ni0 + bi_n + r0 * (nh0 + bh_n)); \
        float hv0 = (1.f - z0) * n0 + z0 * hold0; hold0 = hv0; \
        unsigned short hb0 = f2bf(hv0); \
        h2p[(unsigned)tt * 1024 + rowb * 128 + cb] = hb0; \
        hf[RD ^ 1][(kc_ * 64 + kq_ * 16 + rowb) * 8 + jj] = (short)hb0; \
        float r1 = sigmf(r1x + b_r), z1 = sigmf(z1x + b_z); \
        float n1 = tanh2(ni1 + bi_n + r1 * (nh1 + bh_n)); \
        float hv1 = (1.f - z1) * n1 + z1 * hold1; hold1 = hv1; \
        unsigned short hb1 = f2bf(hv1); \
        h2p[(unsigned)tt * 1024 + (rowb + 1) * 128 + cb] = hb1; \
        hf[RD ^ 1][(kc_ * 64 + kq_ * 16 + rowb + 1) * 8 + jj] = (short)hb1; \
        float p0 = hv0 * tg0, p1 = hv1 * tg1; \
        _Pragma("unroll") for (int off = 1; off < 16; off <<= 1) { \
            p0 += __shfl_xor(p0, off); p1 += __shfl_xor(p1, off); \
        } \
        if ((lane & 15) == 0) { \
            scoreb[RD][rowb * 8 + w] = p0; \
            scoreb[RD][(rowb + 1) * 8 + w] = p1; \
        } \
    } \
    BAR(); \
}

    for (int t2 = 0; t2 < LL / 2; ++t2) {
        GSTEP(2 * t2,     0, xB0, xB1, xB2, xB3, xA0, xA1, xA2, xA3);
        GSTEP(2 * t2 + 1, 1, xA0, xA1, xA2, xA3, xB0, xB1, xB2, xB3);
    }
#undef GSTEP
#undef XLOAD
    if (lane == 16) {  // final score (tt=199, parity 1)
        float s = 0.f;
#pragma unroll
        for (int wv = 0; wv < 8; ++wv) s += scoreb[1][w * 8 + wv];
        scores[(size_t)(b0 + w) * LL + LL - 1] = s * 0.08838834764831845f;
    }
}

// ---- K4: AUGRU scan v10 — inline softmax prologue, natural-layout x gather ----
__global__ __launch_bounds__(512, 2) void augru_v10(
    const unsigned short* __restrict__ h2, const float* __restrict__ scores,
    const int* __restrict__ hseq,
    const float* __restrict__ Wr, const float* __restrict__ Wu,
    const float* __restrict__ Wht,
    const float* __restrict__ br, const float* __restrict__ bu,
    const float* __restrict__ bh, float* __restrict__ evolved) {
    __shared__ alignas(16) unsigned short hf[2][2048];
    __shared__ alignas(16) unsigned short rhf[2048];
    __shared__ float attl[GR * LL];
    const int tid = threadIdx.x;
    const int w = tid >> 6, lane = tid & 63;
    const int b0 = blockIdx.x * GR;
    const int cb = (w << 4) | (lane & 15);
    const int kc_ = cb >> 5, kq_ = (cb >> 3) & 3, jj = cb & 7;
    const int srcl = lane & 31;
    const bool hi = lane >= 32;
    const int rowb = ((lane & 31) >> 4) * 4 + (hi ? 2 : 0);
    // natural-layout A-frag gather: row = lane&7, dims (lane>>4)*8 + kc*32
    const unsigned lofs = (unsigned)((lane & 7) * 256 + (lane >> 4) * 16);
    const char* const h2c = (const char*)(h2 + (size_t)blockIdx.x * (LL * 1024));
    s16x8 wr_[8], wu_[8], wx_[4], wh_[4];
    {
        int c = lane & 15, kg = (lane >> 4) * 8;
        int r0 = w * 16 + c;
#pragma unroll
        for (int kc = 0; kc < 8; ++kc) {
            wr_[kc] = pack8g(Wr + (size_t)r0 * 256 + kc * 32 + kg);
            wu_[kc] = pack8g(Wu + (size_t)r0 * 256 + kc * 32 + kg);
        }
#pragma unroll
        for (int kc = 0; kc < 4; ++kc) {
            wx_[kc] = pack8g(Wht + (size_t)r0 * 256 + kc * 32 + kg);
            wh_[kc] = pack8g(Wht + (size_t)r0 * 256 + 128 + kc * 32 + kg);
        }
    }
    const float br_c = br[cb], bu_c = bu[cb], bh_c = bh[cb];
    float hold0 = 0.f, hold1 = 0.f;
    for (int i = tid; i < 2048; i += 512) { hf[0][i] = 0; hf[1][i] = 0; rhf[i] = 0; }
    {   // inline masked softmax: wave w -> row w
        float vv[4];
#pragma unroll
        for (int m = 0; m < 4; ++m) {
            int t = lane + 64 * m;
            if (t < LL) {
                float s = scores[(size_t)(b0 + w) * LL + t];
                vv[m] = (hseq[(size_t)(b0 + w) * LL + t] > 0) ? s : -1e9f;
            } else
                vv[m] = -3.0e38f;
        }
        float mx = fmaxf(fmaxf(vv[0], vv[1]), fmaxf(vv[2], vv[3]));
        for (int off = 1; off < 64; off <<= 1) mx = fmaxf(mx, __shfl_xor(mx, off));
        float ssum = 0.f;
#pragma unroll
        for (int m = 0; m < 4; ++m) {
            int t = lane + 64 * m;
            vv[m] = (t < LL) ? __expf(vv[m] - mx) : 0.f;
            ssum += vv[m];
        }
        for (int off = 1; off < 64; off <<= 1) ssum += __shfl_xor(ssum, off);
        float inv = fastrcp(ssum);
#pragma unroll
        for (int m = 0; m < 4; ++m) {
            int t = lane + 64 * m;
            if (t < LL) attl[w * LL + t] = vv[m] * inv;  // masked -> exactly 0
        }
    }
    __syncthreads();

    s16x8 xA0, xA1, xA2, xA3, xB0, xB1, xB2, xB3;
    f32x4 xr, xu, xx;
#define XLOADA(TT, X0, X1, X2, X3) { \
    const char* xp_ = h2c + (unsigned)(TT) * 2048 + lofs; \
    X0 = *(const s16x8*)(xp_);       X1 = *(const s16x8*)(xp_ + 64); \
    X2 = *(const s16x8*)(xp_ + 128); X3 = *(const s16x8*)(xp_ + 192); \
}
    XLOADA(0, xA0, xA1, xA2, xA3);
    xr = (f32x4){0, 0, 0, 0}; xu = xr; xx = xr;
    xr = MFMA(xA0, wr_[0], xr); xu = MFMA(xA0, wu_[0], xu); xx = MFMA(xA0, wx_[0], xx);
    xr = MFMA(xA1, wr_[1], xr); xu = MFMA(xA1, wu_[1], xu); xx = MFMA(xA1, wx_[1], xx);
    xr = MFMA(xA2, wr_[2], xr); xu = MFMA(xA2, wu_[2], xu); xx = MFMA(xA2, wx_[2], xx);
    xr = MFMA(xA3, wr_[3], xr); xu = MFMA(xA3, wu_[3], xu); xx = MFMA(xA3, wx_[3], xx);
    XLOADA(1, xB0, xB1, xB2, xB3);

#define ASTEP(TT, RD, XU0, XU1, XU2, XU3, XL0, XL1, XL2, XL3) { \
    const int tt = (TT); \
    f32x4 ar = xr, au = xu, ax = xx; \
    _Pragma("unroll") for (int kc = 0; kc < 4; ++kc) { \
        s16x8 ha = *(const s16x8*)&hf[RD][(kc * 64 + lane) * 8]; \
        ar = MFMA(ha, wr_[kc + 4], ar); au = MFMA(ha, wu_[kc + 4], au); \
    } \
    xr = (f32x4){0, 0, 0, 0}; xu = xr; xx = xr; \
    xr = MFMA(XU0, wr_[0], xr); xu = MFMA(XU0, wu_[0], xu); xx = MFMA(XU0, wx_[0], xx); \
    xr = MFMA(XU1, wr_[1], xr); xu = MFMA(XU1, wu_[1], xu); xx = MFMA(XU1, wx_[1], xx); \
    xr = MFMA(XU2, wr_[2], xr); xu = MFMA(XU2, wu_[2], xu); xx = MFMA(XU2, wx_[2], xx); \
    xr = MFMA(XU3, wr_[3], xr); xu = MFMA(XU3, wu_[3], xu); xx = MFMA(XU3, wx_[3], xx); \
    XLOADA(tt + 2 < LL ? tt + 2 : LL - 1, XL0, XL1, XL2, XL3); \
    { \
        float a0, a1; \
        RED2(ar, a0, a1); \
        float r0 = sigmf(a0 + br_c), r1 = sigmf(a1 + br_c); \
        rhf[(kc_ * 64 + kq_ * 16 + rowb) * 8 + jj] = (short)f2bf(r0 * hold0); \
        rhf[(kc_ * 64 + kq_ * 16 + rowb + 1) * 8 + jj] = (short)f2bf(r1 * hold1); \
    } \
    BAR(); \
    f32x4 ah = {0, 0, 0, 0}; \
    _Pragma("unroll") for (int kc = 0; kc < 4; ++kc) { \
        s16x8 ra = *(const s16x8*)&rhf[(kc * 64 + lane) * 8]; \
        ah = MFMA(ra, wh_[kc], ah); \
    } \
    { \
        float u0, u1, t0, t1, g0, g1; \
        RED2(au, u0, u1); RED2(ax, t0, t1); RED2(ah, g0, g1); \
        float uu0 = sigmf(u0 + bu_c), uu1 = sigmf(u1 + bu_c); \
        float up0 = attl[rowb * LL + tt] * uu0; \
        float up1 = attl[(rowb + 1) * LL + tt] * uu1; \
        float ht0 = tanh2(t0 + g0 + bh_c), ht1 = tanh2(t1 + g1 + bh_c); \
        hold0 = (1.f - up0) * hold0 + up0 * ht0; \
        hold1 = (1.f - up1) * hold1 + up1 * ht1; \
        hf[RD ^ 1][(kc_ * 64 + kq_ * 16 + rowb) * 8 + jj] = (short)f2bf(hold0); \
        hf[RD ^ 1][(kc_ * 64 + kq_ * 16 + rowb + 1) * 8 + jj] = (short)f2bf(hold1); \
    } \
    BAR(); \
}

    for (int t2 = 0; t2 < LL / 2; ++t2) {
        ASTEP(2 * t2,     0, xB0, xB1, xB2, xB3, xA0, xA1, xA2, xA3);
        ASTEP(2 * t2 + 1, 1, xA0, xA1, xA2, xA3, xB0, xB1, xB2, xB3);
    }
#undef ASTEP
#undef XLOADA
    evolved[(size_t)(b0 + rowb) * 128 + cb] = hold0;
    evolved[(size_t)(b0 + rowb + 1) * 128 + cb] = hold1;
}

// ---- K5: feature concat + 3-layer MLP + sigmoid ----
__global__ __launch_bounds__(256) void mlp_kernel(
    const int* __restrict__ user_id, const int* __restrict__ item_id,
    const int* __restrict__ item_cat, const int* __restrict__ item_dur,
    const float* __restrict__ user_dense, const float* __restrict__ item_dense,
    const float* __restrict__ user_table, const float* __restrict__ item_table,
    const float* __restrict__ cat_table, const float* __restrict__ dur_table,
    const float* __restrict__ evolved,
    const float* __restrict__ W1t, const float* __restrict__ b1,
    const float* __restrict__ W2t, const float* __restrict__ b2,
    const float* __restrict__ W3, const float* __restrict__ b3,
    float* __restrict__ out) {
    __shared__ float Xs[MR][332];
    __shared__ float h1s[MR][256];
    __shared__ float h2s[MR][128];
    __shared__ int ids[4][MR];
    const int tid = threadIdx.x;
    const int b0 = blockIdx.x * MR;
    if (tid < MR) {
        ids[0][tid] = user_id[b0 + tid];
        ids[1][tid] = item_id[b0 + tid];
        ids[2][tid] = item_cat[b0 + tid];
        ids[3][tid] = item_dur[b0 + tid];
    }
    __syncthreads();
    for (int i = tid; i < MR * 332; i += 256) {
        int r = i / 332, c = i % 332;
        int b = b0 + r;
        float v;
        if (c < 64) v = user_table[(size_t)ids[0][r] * 64 + c];
        else if (c < 128) v = item_table[(size_t)ids[1][r] * 64 + (c - 64)];
        else if (c < 160) v = cat_table[(size_t)ids[2][r] * 32 + (c - 128)];
        else if (c < 176) v = dur_table[(size_t)ids[3][r] * 16 + (c - 160)];
        else if (c < 201) v = user_dense[(size_t)b * 25 + (c - 176)];
        else if (c < 204) v = item_dense[(size_t)b * 3 + (c - 201)];
        else v = evolved[(size_t)b * 128 + (c - 204)];
        Xs[r][c] = v;
    }
    __syncthreads();
    {
        float acc[MR] = {0, 0, 0, 0, 0, 0, 0, 0};
        for (int k = 0; k < 332; ++k) {
            float ww = W1t[(size_t)k * 256 + tid];
#pragma unroll
            for (int r = 0; r < MR; ++r) acc[r] += Xs[r][k] * ww;
        }
        float bb = b1[tid];
#pragma unroll
        for (int r = 0; r < MR; ++r) h1s[r][tid] = fmaxf(acc[r] + bb, 0.f);
    }
    __syncthreads();
    if (tid < 128) {
        float acc[MR] = {0, 0, 0, 0, 0, 0, 0, 0};
        for (int k = 0; k < 256; ++k) {
            float ww = W2t[(size_t)k * 128 + tid];
#pragma unroll
            for (int r = 0; r < MR; ++r) acc[r] += h1s[r][k] * ww;
        }
        float bb = b2[tid];
#pragma unroll
        for (int r = 0; r < MR; ++r) h2s[r][tid] = fmaxf(acc[r] + bb, 0.f);
    }
    __syncthreads();
    {
        int r = tid >> 5, j = tid & 31;
        float p = 0.f;
#pragma unroll
        for (int m = 0; m < 4; ++m) p += h2s[r][j + 32 * m] * W3[j + 32 * m];
        p += __shfl_xor(p, 16);
        p += __shfl_xor(p, 8);
        p += __shfl_xor(p, 4);
        p += __shfl_xor(p, 2);
        p += __shfl_xor(p, 1);
        if (j == 0) out[b0 + r] = 1.f / (1.f + __expf(-(p + b3[0])));
    }
}

extern "C" void kernel_launch(void* const* d_in, const int* in_sizes, int n_in,
                              void* d_out, int out_size, void* d_ws, size_t ws_size,
                              hipStream_t stream) {
    const int* user_id = (const int*)d_in[0];
    const int* item_id = (const int*)d_in[1];
    const int* item_cat = (const int*)d_in[2];
    const int* item_dur = (const int*)d_in[3];
    const int* hseq = (const int*)d_in[4];
    const float* user_dense = (const float*)d_in[5];
    const float* item_dense = (const float*)d_in[6];
    const float* user_table = (const float*)d_in[7];
    const float* item_table = (const float*)d_in[8];
    const float* cat_table = (const float*)d_in[9];
    const float* dur_table = (const float*)d_in[10];
    const float* hist_table = (const float*)d_in[11];
    const float* projW = (const float*)d_in[12];
    const float* gWi = (const float*)d_in[13];
    const float* gWh = (const float*)d_in[14];
    const float* gbi = (const float*)d_in[15];
    const float* gbh = (const float*)d_in[16];
    const float* aWr = (const float*)d_in[17];
    const float* abr = (const float*)d_in[18];
    const float* aWu = (const float*)d_in[19];
    const float* abu = (const float*)d_in[20];
    const float* aWh = (const float*)d_in[21];
    const float* abh = (const float*)d_in[22];
    const float* mW1 = (const float*)d_in[23];
    const float* mb1 = (const float*)d_in[24];
    const float* mW2 = (const float*)d_in[25];
    const float* mb2 = (const float*)d_in[26];
    const float* mW3 = (const float*)d_in[27];
    const float* mb3 = (const float*)d_in[28];
    float* out = (float*)d_out;

    float* ws = (float*)d_ws;
    float* target = ws;                                     // 262144 f
    unsigned short* h2 = (unsigned short*)(ws + 262144);    // 256*200*1024 shorts
    float* scores = ws + 262144 + 26214400;                 // 409600 f
    float* evolved = scores + 409600;                       // 262144 f
    float* W1t = evolved + 262144;                          // 84992 f
    float* W2t = W1t + 84992;                               // 32768 f
    unsigned short* hist_bf = (unsigned short*)(W2t + 32768);  // 6400064 f-slots

    const int n8 = 100001 * 16;  // (N_ITEMS+1)*128/8
    hipLaunchKernelGGL(cvt_hist, dim3((n8 + 255) / 256), dim3(256), 0, stream,
                       hist_table, hist_bf, n8);
    hipLaunchKernelGGL(transpose_kernel, dim3(332), dim3(256), 0, stream, mW1, W1t, 256, 332);
    hipLaunchKernelGGL(transpose_kernel, dim3(256), dim3(128), 0, stream, mW2, W2t, 128, 256);
    hipLaunchKernelGGL(target_kernel, dim3(2048), dim3(128), 0, stream,
                       item_id, item_table, projW, target);
    hipLaunchKernelGGL(gru_v10, dim3(BB / GR), dim3(512), 0, stream,
                       hseq, hist_bf, gWi, gWh, gbi, gbh, target, h2, scores);
    hipLaunchKernelGGL(augru_v10, dim3(BB / GR), dim3(512), 0, stream,
                       h2, scores, hseq, aWr, aWu, aWh, abr, abu, abh, evolved);
    hipLaunchKernelGGL(mlp_kernel, dim3(BB / MR), dim3(256), 0, stream,
                       user_id, item_id, item_cat, item_dur, user_dense, item_dense,
                       user_table, item_table, cat_table, dur_table, evolved,
                       W1t, mb1, W2t, mb2, mW3, mb3, out);
}

// Round 11
// 450.281 us; speedup vs baseline: 1.0948x; 1.0948x over previous
//
#include <hip/hip_runtime.h>
#include <cstdint>
#include <cstddef>

// ---- problem constants ----
#define BB    2048
#define LL    200
#define GR    8      // batch rows per scan block
#define MR    8      // batch rows per block in MLP

typedef __attribute__((ext_vector_type(4))) float f32x4;
typedef __attribute__((ext_vector_type(8))) short s16x8;

__device__ __forceinline__ float fastrcp(float x) { return __builtin_amdgcn_rcpf(x); }
__device__ __forceinline__ float sigmf(float x) { return fastrcp(1.f + __expf(-x)); }
__device__ __forceinline__ float tanh2(float x) {
    return __builtin_fmaf(2.f, fastrcp(1.f + __expf(-2.f * x)), -1.f);
}
__device__ __forceinline__ float dot4(float4 a, float4 b) {
    return a.x * b.x + a.y * b.y + a.z * b.z + a.w * b.w;
}
__device__ __forceinline__ float4 ld4(const float* p) { return *(const float4*)p; }

__device__ __forceinline__ unsigned short f2bf(float f) {  // RNE
    union { float f; unsigned u; } v; v.f = f;
    unsigned r = (v.u + 0x7FFFu + ((v.u >> 16) & 1u)) >> 16;
    return (unsigned short)r;
}
__device__ __forceinline__ float bf2f(unsigned short b) {
    unsigned u = ((unsigned)b) << 16;
    union { unsigned u; float f; } v; v.u = u;
    return v.f;
}
__device__ __forceinline__ s16x8 pack8g(const float* p) {
    float4 a = ld4(p), b = ld4(p + 4);
    s16x8 o;
    o[0] = (short)f2bf(a.x); o[1] = (short)f2bf(a.y);
    o[2] = (short)f2bf(a.z); o[3] = (short)f2bf(a.w);
    o[4] = (short)f2bf(b.x); o[5] = (short)f2bf(b.y);
    o[6] = (short)f2bf(b.z); o[7] = (short)f2bf(b.w);
    return o;
}
#define MFMA(a, b, c) __builtin_amdgcn_mfma_f32_16x16x32_bf16((a), (b), (c), 0, 0, 0)

// Raw barrier: LDS-drain only; global prefetch loads stay in flight.
#define BAR() do { \
    asm volatile("s_waitcnt lgkmcnt(0)" ::: "memory"); \
    __builtin_amdgcn_sched_barrier(0); \
    __builtin_amdgcn_s_barrier(); \
    __builtin_amdgcn_sched_barrier(0); \
} while (0)

// redistribute f32x4 acc (8 rows spread as lanes0-31:q0..3) -> every lane 2 rows
#define RED2(A, O0, O1) { \
    float s2_ = __shfl(A[2], srcl), s3_ = __shfl(A[3], srcl); \
    O0 = hi ? s2_ : A[0]; O1 = hi ? s3_ : A[1]; \
}

// ---- K-1: convert hist_table fp32 -> bf16 once ----
__global__ __launch_bounds__(256) void cvt_hist(const float* __restrict__ src,
                                                unsigned short* __restrict__ dst, int n8) {
    int i = blockIdx.x * 256 + threadIdx.x;
    if (i < n8) *(s16x8*)(dst + (size_t)i * 8) = pack8g(src + (size_t)i * 8);
}

// ---- K0: transpose small weight matrices ----
__global__ void transpose_kernel(const float* __restrict__ src, float* __restrict__ dst,
                                 int rows, int cols) {
    int k = blockIdx.x;
    for (int j = threadIdx.x; j < rows; j += blockDim.x)
        dst[(size_t)k * rows + j] = src[(size_t)j * cols + k];
}

// ---- K1: target = item_table[item_id] @ proj_W^T ----
__global__ __launch_bounds__(128) void target_kernel(
    const int* __restrict__ item_id, const float* __restrict__ item_table,
    const float* __restrict__ projW, float* __restrict__ target) {
    __shared__ float ie[64];
    int b = blockIdx.x, d = threadIdx.x;
    if (d < 64) ie[d] = item_table[(size_t)item_id[b] * 64 + d];
    __syncthreads();
    float acc = 0.f;
    const float* w = projW + (size_t)d * 64;
#pragma unroll
    for (int k = 0; k < 64; k += 4) acc += dot4(ld4(&ie[k]), ld4(w + k));
    target[(size_t)b * 128 + d] = acc;
}

// ---- K2: GRU scan v6 — GR=8, (512,2), merged r/z, frag-compact h flush ----
// h2 layout: per (block, t): 1024 shorts, cell tid*8+j = h[row=tid&7][d],
// d = (tid>>5)*32 + ((tid>>3)&3)*8 + j   (== the 16x16x32 A-frag cells, rows 0-7)
__global__ __launch_bounds__(512, 2) void gru_v6(
    const int* __restrict__ hseq, const unsigned short* __restrict__ hist_bf,
    const float* __restrict__ Wi, const float* __restrict__ Wh,
    const float* __restrict__ bi, const float* __restrict__ bh,
    unsigned short* __restrict__ h2) {
    __shared__ alignas(16) unsigned short xf[2][2048];
    __shared__ alignas(16) unsigned short hf[2][2048];
    __shared__ int sq[GR * LL];
    const int tid = threadIdx.x;
    const int w = tid >> 6, lane = tid & 63;
    const int b0 = blockIdx.x * GR;
    const int cb = (w << 4) | (lane & 15);
    const int kc_ = cb >> 5, kq_ = (cb >> 3) & 3, jj = cb & 7;
    const int srcl = lane & 31;
    const bool hi = lane >= 32;
    const int rowb = ((lane & 31) >> 4) * 4 + (hi ? 2 : 0);  // rows rowb, rowb+1
    const int fs = ((tid >> 5) * 64 + ((tid >> 3) & 3) * 16 + (tid & 7)) * 8;  // flush src (tid<128)
    unsigned short* const h2p = h2 + (size_t)blockIdx.x * (LL * 1024);
    // persistent weight fragments (96 VGPR)
    s16x8 wir[4], wiz[4], win[4], whr[4], whz[4], whn[4];
    {
        int c = lane & 15, kg = (lane >> 4) * 8;
#pragma unroll
        for (int kc = 0; kc < 4; ++kc) {
            int ko = kc * 32 + kg;
            wir[kc] = pack8g(Wi + (size_t)(w * 16 + c) * 128 + ko);
            wiz[kc] = pack8g(Wi + (size_t)(128 + w * 16 + c) * 128 + ko);
            win[kc] = pack8g(Wi + (size_t)(256 + w * 16 + c) * 128 + ko);
            whr[kc] = pack8g(Wh + (size_t)(w * 16 + c) * 128 + ko);
            whz[kc] = pack8g(Wh + (size_t)(128 + w * 16 + c) * 128 + ko);
            whn[kc] = pack8g(Wh + (size_t)(256 + w * 16 + c) * 128 + ko);
        }
    }
    const float b_r = bi[cb] + bh[cb];
    const float b_z = bi[128 + cb] + bh[128 + cb];
    const float bi_n = bi[256 + cb], bh_n = bh[256 + cb];
    float hold0 = 0.f, hold1 = 0.f;
    for (int i = tid; i < 2048; i += 512) {
        xf[0][i] = 0; xf[1][i] = 0; hf[0][i] = 0; hf[1][i] = 0;
    }
    for (int i = tid; i < GR * LL; i += 512)
        sq[i] = hseq[(size_t)(b0 + i / LL) * LL + i % LL];
    __syncthreads();
    s16x8 pA, pB;
    if (lane < 16) {   // wave w stages batch row w
        unsigned o0 = (unsigned)sq[w * LL + 0] << 7;
        *(s16x8*)&xf[0][(((lane >> 2) * 64) + (lane & 3) * 16 + w) * 8] =
            *(const s16x8*)(hist_bf + o0 + lane * 8);
        unsigned o1 = (unsigned)sq[w * LL + 1] << 7;
        pA = *(const s16x8*)(hist_bf + o1 + lane * 8);
    }
    __syncthreads();

#define GSTEP(TT, RD, CUR, NXT) { \
    const int tt = (TT); \
    if (lane < 16) { \
        *(s16x8*)&xf[RD ^ 1][(((lane >> 2) * 64) + (lane & 3) * 16 + w) * 8] = CUR; \
        unsigned no = (unsigned)sq[w * LL + (tt + 2 < LL ? tt + 2 : LL - 1)] << 7; \
        NXT = *(const s16x8*)(hist_bf + no + lane * 8); \
    } \
    if (tt > 0 && tid < 128) {  /* flush h(tt) = h_states[tt-1] */ \
        s16x8 hv = *(const s16x8*)&hf[RD][fs]; \
        *(s16x8*)(h2p + (unsigned)(tt - 1) * 1024 + tid * 8) = hv; \
    } \
    f32x4 ar = {0,0,0,0}, az = {0,0,0,0}, ain = {0,0,0,0}, ahn = {0,0,0,0}; \
    _Pragma("unroll") for (int kc = 0; kc < 4; ++kc) { \
        s16x8 xa = *(const s16x8*)&xf[RD][(kc * 64 + lane) * 8]; \
        s16x8 ha = *(const s16x8*)&hf[RD][(kc * 64 + lane) * 8]; \
        ar = MFMA(xa, wir[kc], ar); ar = MFMA(ha, whr[kc], ar); \
        az = MFMA(xa, wiz[kc], az); az = MFMA(ha, whz[kc], az); \
        ain = MFMA(xa, win[kc], ain); ahn = MFMA(ha, whn[kc], ahn); \
    } \
    { \
        float r0x, r1x, z0x, z1x, ni0, ni1, nh0, nh1; \
        RED2(ar, r0x, r1x); RED2(az, z0x, z1x); \
        RED2(ain, ni0, ni1); RED2(ahn, nh0, nh1); \
        float r0 = sigmf(r0x + b_r), z0 = sigmf(z0x + b_z); \
        float n0 = tanh2(ni0 + bi_n + r0 * (nh0 + bh_n)); \
        float hv0 = (1.f - z0) * n0 + z0 * hold0; hold0 = hv0; \
        hf[RD ^ 1][(kc_ * 64 + kq_ * 16 + rowb) * 8 + jj] = (short)f2bf(hv0); \
        float r1 = sigmf(r1x + b_r), z1 = sigmf(z1x + b_z); \
        float n1 = tanh2(ni1 + bi_n + r1 * (nh1 + bh_n)); \
        float hv1 = (1.f - z1) * n1 + z1 * hold1; hold1 = hv1; \
        hf[RD ^ 1][(kc_ * 64 + kq_ * 16 + rowb + 1) * 8 + jj] = (short)f2bf(hv1); \
    } \
    BAR(); \
}

    for (int t2 = 0; t2 < LL / 2; ++t2) {
        GSTEP(2 * t2,     0, pA, pB);
        GSTEP(2 * t2 + 1, 1, pB, pA);
    }
#undef GSTEP
    if (tid < 128) {  // record LL-1 = h(LL)
        s16x8 hv = *(const s16x8*)&hf[0][fs];
        *(s16x8*)(h2p + (unsigned)(LL - 1) * 1024 + tid * 8) = hv;
    }
}

// ---- K3: scores from frag-compact h2 + masked softmax (block = 8 rows) ----
__global__ __launch_bounds__(512) void score_softmax2(
    const unsigned short* __restrict__ h2, const float* __restrict__ target,
    const int* __restrict__ hseq, float* __restrict__ attn) {
    __shared__ float tg[8][128];
    __shared__ float sA[8][LL];
    __shared__ float sB[8][LL];
    const int tid = threadIdx.x;
    const int blk = blockIdx.x;
    const int b0 = blk * 8;
    {
        int r = tid >> 6, d2 = (tid & 63) * 2;
        tg[r][d2] = target[(size_t)(b0 + r) * 128 + d2];
        tg[r][d2 + 1] = target[(size_t)(b0 + r) * 128 + d2 + 1];
    }
    __syncthreads();
    const unsigned short* const hp = h2 + (size_t)blk * (LL * 1024);
    const int g = tid >> 7;          // 4 t-groups
    const int u = tid & 127;
    const int row = u & 7;
    const int d0 = (u >> 5) * 32 + ((u >> 3) & 3) * 8;
    const int half = u >> 6;         // which wave of the pair
    for (int t = g; t < LL; t += 4) {
        s16x8 hv = *(const s16x8*)(hp + (unsigned)t * 1024 + u * 8);
        float acc = 0.f;
#pragma unroll
        for (int j = 0; j < 8; ++j)
            acc = __builtin_fmaf(bf2f((unsigned short)hv[j]), tg[row][d0 + j], acc);
        acc += __shfl_xor(acc, 8);
        acc += __shfl_xor(acc, 16);
        acc += __shfl_xor(acc, 32);
        if ((u & 63) < 8) { (half ? sB : sA)[row][t] = acc; }
    }
    __syncthreads();
    // per-row masked softmax: wave wv handles row wv
    const int wv = tid >> 6, lane = tid & 63;
    float v[4];
#pragma unroll
    for (int m = 0; m < 4; ++m) {
        int t = lane + 64 * m;
        if (t < LL) {
            float s = (sA[wv][t] + sB[wv][t]) * 0.08838834764831845f;
            v[m] = (hseq[(size_t)(b0 + wv) * LL + t] > 0) ? s : -1e9f;
        } else
            v[m] = -3.0e38f;
    }
    float mx = fmaxf(fmaxf(v[0], v[1]), fmaxf(v[2], v[3]));
    for (int off = 1; off < 64; off <<= 1) mx = fmaxf(mx, __shfl_xor(mx, off));
    float s = 0.f;
#pragma unroll
    for (int m = 0; m < 4; ++m) {
        int t = lane + 64 * m;
        v[m] = (t < LL) ? __expf(v[m] - mx) : 0.f;
        s += v[m];
    }
    for (int off = 1; off < 64; off <<= 1) s += __shfl_xor(s, off);
    float inv = fastrcp(s);
#pragma unroll
    for (int m = 0; m < 4; ++m) {
        int t = lane + 64 * m;
        if (t < LL) attn[(size_t)(b0 + wv) * LL + t] = v[m] * inv;
    }
}

// ---- K4: AUGRU scan v6 — GR=8, (512,2), straight-copy staging from h2 ----
__global__ __launch_bounds__(512, 2) void augru_v6(
    const unsigned short* __restrict__ h2, const float* __restrict__ attn,
    const int* __restrict__ hseq,
    const float* __restrict__ Wr, const float* __restrict__ Wu,
    const float* __restrict__ Wht,
    const float* __restrict__ br, const float* __restrict__ bu,
    const float* __restrict__ bh, float* __restrict__ evolved) {
    __shared__ alignas(16) unsigned short xf[2][2048];
    __shared__ alignas(16) unsigned short hf[2][2048];
    __shared__ alignas(16) unsigned short rhf[2048];
    __shared__ float attl[GR * LL];
    __shared__ float mskl[GR * LL];
    const int tid = threadIdx.x;
    const int w = tid >> 6, lane = tid & 63;
    const int b0 = blockIdx.x * GR;
    const int cb = (w << 4) | (lane & 15);
    const int kc_ = cb >> 5, kq_ = (cb >> 3) & 3, jj = cb & 7;
    const int srcl = lane & 31;
    const bool hi = lane >= 32;
    const int rowb = ((lane & 31) >> 4) * 4 + (hi ? 2 : 0);
    const int fs = ((tid >> 5) * 64 + ((tid >> 3) & 3) * 16 + (tid & 7)) * 8;  // tid<128
    const unsigned short* const h2p = h2 + (size_t)blockIdx.x * (LL * 1024);
    s16x8 wr_[8], wu_[8], wx_[4], wh_[4];
    {
        int c = lane & 15, kg = (lane >> 4) * 8;
        int r0 = w * 16 + c;
#pragma unroll
        for (int kc = 0; kc < 8; ++kc) {
            wr_[kc] = pack8g(Wr + (size_t)r0 * 256 + kc * 32 + kg);
            wu_[kc] = pack8g(Wu + (size_t)r0 * 256 + kc * 32 + kg);
        }
#pragma unroll
        for (int kc = 0; kc < 4; ++kc) {
            wx_[kc] = pack8g(Wht + (size_t)r0 * 256 + kc * 32 + kg);
            wh_[kc] = pack8g(Wht + (size_t)r0 * 256 + 128 + kc * 32 + kg);
        }
    }
    const float br_c = br[cb], bu_c = bu[cb], bh_c = bh[cb];
    float hold0 = 0.f, hold1 = 0.f;
    for (int i = tid; i < 2048; i += 512) {
        xf[0][i] = 0; xf[1][i] = 0; hf[0][i] = 0; hf[1][i] = 0; rhf[i] = 0;
    }
    for (int i = tid; i < GR * LL; i += 512) {
        int r = i / LL, t = i % LL;
        attl[i] = attn[(size_t)(b0 + r) * LL + t];
        mskl[i] = (hseq[(size_t)(b0 + r) * LL + t] > 0) ? 1.f : 0.f;
    }
    __syncthreads();
    s16x8 pA, pB;
    if (tid < 128) {   // straight copy: record t is already A-frag cells
        *(s16x8*)&xf[0][fs] = *(const s16x8*)(h2p + tid * 8);
        pA = *(const s16x8*)(h2p + 1024 + tid * 8);
    }
    __syncthreads();

#define ASTEP(TT, RD, CUR, NXT) { \
    const int tt = (TT); \
    if (tid < 128) { \
        *(s16x8*)&xf[RD ^ 1][fs] = CUR; \
        unsigned nt = (tt + 2 < LL ? tt + 2 : LL - 1); \
        NXT = *(const s16x8*)(h2p + nt * 1024 + tid * 8); \
    } \
    f32x4 ar = {0,0,0,0}, au = {0,0,0,0}, ax = {0,0,0,0}; \
    _Pragma("unroll") for (int kc = 0; kc < 4; ++kc) { \
        s16x8 xa = *(const s16x8*)&xf[RD][(kc * 64 + lane) * 8]; \
        s16x8 ha = *(const s16x8*)&hf[RD][(kc * 64 + lane) * 8]; \
        ar = MFMA(xa, wr_[kc], ar); ar = MFMA(ha, wr_[kc + 4], ar); \
        au = MFMA(xa, wu_[kc], au); au = MFMA(ha, wu_[kc + 4], au); \
        ax = MFMA(xa, wx_[kc], ax); \
    } \
    { \
        float a0, a1; \
        RED2(ar, a0, a1); \
        float r0 = sigmf(a0 + br_c), r1 = sigmf(a1 + br_c); \
        rhf[(kc_ * 64 + kq_ * 16 + rowb) * 8 + jj] = (short)f2bf(r0 * hold0); \
        rhf[(kc_ * 64 + kq_ * 16 + rowb + 1) * 8 + jj] = (short)f2bf(r1 * hold1); \
    } \
    BAR(); \
    f32x4 ah = {0,0,0,0}; \
    _Pragma("unroll") for (int kc = 0; kc < 4; ++kc) { \
        s16x8 ra = *(const s16x8*)&rhf[(kc * 64 + lane) * 8]; \
        ah = MFMA(ra, wh_[kc], ah); \
    } \
    { \
        float u0, u1, x0, x1, g0, g1; \
        RED2(au, u0, u1); RED2(ax, x0, x1); RED2(ah, g0, g1); \
        float uu0 = sigmf(u0 + bu_c), uu1 = sigmf(u1 + bu_c); \
        float up0 = attl[rowb * LL + tt] * uu0; \
        float up1 = attl[(rowb + 1) * LL + tt] * uu1; \
        float ht0 = tanh2(x0 + g0 + bh_c), ht1 = tanh2(x1 + g1 + bh_c); \
        float hv0 = (1.f - up0) * hold0 + up0 * ht0; \
        float hv1 = (1.f - up1) * hold1 + up1 * ht1; \
        hold0 = mskl[rowb * LL + tt] > 0.5f ? hv0 : hold0; \
        hold1 = mskl[(rowb + 1) * LL + tt] > 0.5f ? hv1 : hold1; \
        hf[RD ^ 1][(kc_ * 64 + kq_ * 16 + rowb) * 8 + jj] = (short)f2bf(hold0); \
        hf[RD ^ 1][(kc_ * 64 + kq_ * 16 + rowb + 1) * 8 + jj] = (short)f2bf(hold1); \
    } \
    BAR(); \
}

    for (int t2 = 0; t2 < LL / 2; ++t2) {
        ASTEP(2 * t2,     0, pA, pB);
        ASTEP(2 * t2 + 1, 1, pB, pA);
    }
#undef ASTEP
    evolved[(size_t)(b0 + rowb) * 128 + cb] = hold0;
    evolved[(size_t)(b0 + rowb + 1) * 128 + cb] = hold1;
}

// ---- K5: feature concat + 3-layer MLP + sigmoid ----
__global__ __launch_bounds__(256) void mlp_kernel(
    const int* __restrict__ user_id, const int* __restrict__ item_id,
    const int* __restrict__ item_cat, const int* __restrict__ item_dur,
    const float* __restrict__ user_dense, const float* __restrict__ item_dense,
    const float* __restrict__ user_table, const float* __restrict__ item_table,
    const float* __restrict__ cat_table, const float* __restrict__ dur_table,
    const float* __restrict__ evolved,
    const float* __restrict__ W1t, const float* __restrict__ b1,
    const float* __restrict__ W2t, const float* __restrict__ b2,
    const float* __restrict__ W3, const float* __restrict__ b3,
    float* __restrict__ out) {
    __shared__ float Xs[MR][332];
    __shared__ float h1s[MR][256];
    __shared__ float h2s[MR][128];
    __shared__ int ids[4][MR];
    const int tid = threadIdx.x;
    const int b0 = blockIdx.x * MR;
    if (tid < MR) {
        ids[0][tid] = user_id[b0 + tid];
        ids[1][tid] = item_id[b0 + tid];
        ids[2][tid] = item_cat[b0 + tid];
        ids[3][tid] = item_dur[b0 + tid];
    }
    __syncthreads();
    for (int i = tid; i < MR * 332; i += 256) {
        int r = i / 332, c = i % 332;
        int b = b0 + r;
        float v;
        if (c < 64) v = user_table[(size_t)ids[0][r] * 64 + c];
        else if (c < 128) v = item_table[(size_t)ids[1][r] * 64 + (c - 64)];
        else if (c < 160) v = cat_table[(size_t)ids[2][r] * 32 + (c - 128)];
        else if (c < 176) v = dur_table[(size_t)ids[3][r] * 16 + (c - 160)];
        else if (c < 201) v = user_dense[(size_t)b * 25 + (c - 176)];
        else if (c < 204) v = item_dense[(size_t)b * 3 + (c - 201)];
        else v = evolved[(size_t)b * 128 + (c - 204)];
        Xs[r][c] = v;
    }
    __syncthreads();
    {
        float acc[MR] = {0, 0, 0, 0, 0, 0, 0, 0};
        for (int k = 0; k < 332; ++k) {
            float ww = W1t[(size_t)k * 256 + tid];
#pragma unroll
            for (int r = 0; r < MR; ++r) acc[r] += Xs[r][k] * ww;
        }
        float bb = b1[tid];
#pragma unroll
        for (int r = 0; r < MR; ++r) h1s[r][tid] = fmaxf(acc[r] + bb, 0.f);
    }
    __syncthreads();
    if (tid < 128) {
        float acc[MR] = {0, 0, 0, 0, 0, 0, 0, 0};
        for (int k = 0; k < 256; ++k) {
            float ww = W2t[(size_t)k * 128 + tid];
#pragma unroll
            for (int r = 0; r < MR; ++r) acc[r] += h1s[r][k] * ww;
        }
        float bb = b2[tid];
#pragma unroll
        for (int r = 0; r < MR; ++r) h2s[r][tid] = fmaxf(acc[r] + bb, 0.f);
    }
    __syncthreads();
    {
        int r = tid >> 5, j = tid & 31;
        float p = 0.f;
#pragma unroll
        for (int m = 0; m < 4; ++m) p += h2s[r][j + 32 * m] * W3[j + 32 * m];
        p += __shfl_xor(p, 16);
        p += __shfl_xor(p, 8);
        p += __shfl_xor(p, 4);
        p += __shfl_xor(p, 2);
        p += __shfl_xor(p, 1);
        if (j == 0) out[b0 + r] = 1.f / (1.f + __expf(-(p + b3[0])));
    }
}

extern "C" void kernel_launch(void* const* d_in, const int* in_sizes, int n_in,
                              void* d_out, int out_size, void* d_ws, size_t ws_size,
                              hipStream_t stream) {
    const int* user_id = (const int*)d_in[0];
    const int* item_id = (const int*)d_in[1];
    const int* item_cat = (const int*)d_in[2];
    const int* item_dur = (const int*)d_in[3];
    const int* hseq = (const int*)d_in[4];
    const float* user_dense = (const float*)d_in[5];
    const float* item_dense = (const float*)d_in[6];
    const float* user_table = (const float*)d_in[7];
    const float* item_table = (const float*)d_in[8];
    const float* cat_table = (const float*)d_in[9];
    const float* dur_table = (const float*)d_in[10];
    const float* hist_table = (const float*)d_in[11];
    const float* projW = (const float*)d_in[12];
    const float* gWi = (const float*)d_in[13];
    const float* gWh = (const float*)d_in[14];
    const float* gbi = (const float*)d_in[15];
    const float* gbh = (const float*)d_in[16];
    const float* aWr = (const float*)d_in[17];
    const float* abr = (const float*)d_in[18];
    const float* aWu = (const float*)d_in[19];
    const float* abu = (const float*)d_in[20];
    const float* aWh = (const float*)d_in[21];
    const float* abh = (const float*)d_in[22];
    const float* mW1 = (const float*)d_in[23];
    const float* mb1 = (const float*)d_in[24];
    const float* mW2 = (const float*)d_in[25];
    const float* mb2 = (const float*)d_in[26];
    const float* mW3 = (const float*)d_in[27];
    const float* mb3 = (const float*)d_in[28];
    float* out = (float*)d_out;

    float* ws = (float*)d_ws;
    float* target = ws;                                     // 262144 f
    unsigned short* h2 = (unsigned short*)(ws + 262144);    // 256*200*1024 shorts = 26214400 f-slots
    float* attn = ws + 262144 + 26214400;                   // 409600 f
    float* evolved = attn + 409600;                         // 262144 f
    float* W1t = evolved + 262144;                          // 84992 f
    float* W2t = W1t + 84992;                               // 32768 f
    unsigned short* hist_bf = (unsigned short*)(W2t + 32768);  // 6400064 f-slots

    const int n8 = 100001 * 16;  // (N_ITEMS+1)*128/8
    hipLaunchKernelGGL(cvt_hist, dim3((n8 + 255) / 256), dim3(256), 0, stream,
                       hist_table, hist_bf, n8);
    hipLaunchKernelGGL(transpose_kernel, dim3(332), dim3(256), 0, stream, mW1, W1t, 256, 332);
    hipLaunchKernelGGL(transpose_kernel, dim3(256), dim3(128), 0, stream, mW2, W2t, 128, 256);
    hipLaunchKernelGGL(target_kernel, dim3(2048), dim3(128), 0, stream,
                       item_id, item_table, projW, target);
    hipLaunchKernelGGL(gru_v6, dim3(BB / GR), dim3(512), 0, stream,
                       hseq, hist_bf, gWi, gWh, gbi, gbh, h2);
    hipLaunchKernelGGL(score_softmax2, dim3(BB / 8), dim3(512), 0, stream,
                       h2, target, hseq, attn);
    hipLaunchKernelGGL(augru_v6, dim3(BB / GR), dim3(512), 0, stream,
                       h2, attn, hseq, aWr, aWu, aWh, abr, abu, abh, evolved);
    hipLaunchKernelGGL(mlp_kernel, dim3(BB / MR), dim3(256), 0, stream,
                       user_id, item_id, item_cat, item_dur, user_dense, item_dense,
                       user_table, item_table, cat_table, dur_table, evolved,
                       W1t, mb1, W2t, mb2, mW3, mb3, out);
}